// Round 1
// baseline (192.650 us; speedup 1.0000x reference)
//
#include <hip/hip_runtime.h>
#include <hip/hip_bf16.h>

// Problem constants
constexpr int Bc = 32, Sc = 4096, Dc = 64, Pc = 8, STRIDEc = 4, Hc = 512;
constexpr int Tc = (Sc - Pc) / STRIDEc + 1;   // 1023
constexpr int Kc = Pc * Dc;                   // 512
constexpr float EPSc = 1e-6f;
constexpr int PITCH = 40;                     // bf16 LDS row pitch (80B -> 2-way banks = free)

typedef __bf16 bf16x8 __attribute__((ext_vector_type(8)));
typedef unsigned short ushort8 __attribute__((ext_vector_type(8)));
typedef float f32x4 __attribute__((ext_vector_type(4)));

__device__ __forceinline__ int n_tok_of(int len) {
    return (len >= Pc) ? ((len - Pc) / STRIDEc + 1) : 1;
}

// fp32 -> bf16 round-to-nearest-even
__device__ __forceinline__ unsigned short f2bf(float f) {
    unsigned u = __builtin_bit_cast(unsigned, f);
    u = (u + 0x7FFFu + ((u >> 16) & 1u)) >> 16;
    return (unsigned short)u;
}

// ---------------------------------------------------------------------------
// Prep: Wt_s[k0/32][n][k%32] = bf16(W[k][n])  (transposed, k-slice-packed so
// each k-step's B tile is one contiguous 32 KB block; within a slice the MFMA
// fragment layout (n*32 + quad*8) is contiguous 1KB per wave-load).
// grid (16,16) tiles of 32x32, 256 threads.
// ---------------------------------------------------------------------------
__global__ __launch_bounds__(256) void prep_kernel(
        const float* __restrict__ W, const int* __restrict__ lengths,
        unsigned short* __restrict__ Wt, float* __restrict__ out_tl) {
    __shared__ float tile[32][33];
    const int k0 = blockIdx.x * 32, n0 = blockIdx.y * 32;
    const int r = threadIdx.x >> 3, c = (threadIdx.x & 7) * 4;
    const float4 v = *(const float4*)(W + (size_t)(k0 + r) * Hc + n0 + c);
    tile[c + 0][r] = v.x;
    tile[c + 1][r] = v.y;
    tile[c + 2][r] = v.z;
    tile[c + 3][r] = v.w;
    __syncthreads();
    ushort4 o;
    o.x = f2bf(tile[r][c + 0]);
    o.y = f2bf(tile[r][c + 1]);
    o.z = f2bf(tile[r][c + 2]);
    o.w = f2bf(tile[r][c + 3]);
    *(ushort4*)(Wt + (size_t)blockIdx.x * (Hc * 32) + (size_t)(n0 + r) * 32 + c) = o;
    if (blockIdx.x == 0 && blockIdx.y == 0 && threadIdx.x < Bc)
        out_tl[threadIdx.x] = (float)n_tok_of(lengths[threadIdx.x]);
}

// ---------------------------------------------------------------------------
// Fused: tokens-write + bf16-MFMA GEMM (BM=64 x BN=512) + bias + RMSNorm*scale.
// Changes vs previous version:
//  * Masking is exactly row-level (t < ntok => all pos < len). Blocks with
//    t0 >= ntok skip the GEMM entirely: tokens rows are zero, hidden rows are
//    the constant  scale * b / rms(b).
//  * B operand (Wt fragments) loads DIRECTLY from global in fragment layout
//    (1KB coalesced per wave per ct) -- the old global->LDS->reg roundtrip
//    was a pure shuffle of already-fragment-contiguous data. Removes ~75% of
//    LDS traffic. Register double-buffered (rbA/rbB) across k-steps.
//  * A tile double-buffered in LDS (2 x 5KB) -> ONE barrier per k-step.
//  * Nontemporal stores for the 134 MB of streaming output.
// ---------------------------------------------------------------------------
__global__ __launch_bounds__(256, 2) void fused_kernel(
        const float* __restrict__ x, const int* __restrict__ lengths,
        const unsigned short* __restrict__ Wt, const float* __restrict__ bias,
        const float* __restrict__ scale, float* __restrict__ hidden,
        float* __restrict__ tokens) {
    const int b  = blockIdx.y;
    const int t0 = blockIdx.x * 64;
    const int len = lengths[b];
    const int ntok = n_tok_of(len);
    const int tid = threadIdx.x;

    float* tokb = tokens + (size_t)b * Tc * Kc;

    if (t0 >= ntok) {
        // ---- fast path: every row in this block is padding ----
        // hidden row = scale * b / rms(b)   (identical to GEMM path on zeros)
        __shared__ float red[4];
        const int w = tid >> 6, lane = tid & 63;
        const float2 b2 = *(const float2*)(bias + tid * 2);
        float s = b2.x * b2.x + b2.y * b2.y;
#pragma unroll
        for (int off = 32; off; off >>= 1) s += __shfl_xor(s, off);
        if (lane == 0) red[w] = s;
        __syncthreads();
        const float rstd = rsqrtf((red[0] + red[1] + red[2] + red[3])
                                  * (1.0f / (float)Hc) + EPSc);
        const int c4 = (tid & 127) * 4;
        const f32x4 cvec = *(const f32x4*)(bias + c4) * rstd
                         * *(const f32x4*)(scale + c4);
        const f32x4 z = {0.f, 0.f, 0.f, 0.f};
        float* hidb = hidden + ((size_t)b * Tc + t0) * Hc;
        float* tokp = tokb + (size_t)t0 * Kc;
        const int r0 = tid >> 7;                 // 0 or 1: two rows per pass
#pragma unroll 8
        for (int rr = r0; rr < 64; rr += 2) {
            if (t0 + rr < Tc) {
                __builtin_nontemporal_store(cvec, (f32x4*)(hidb + (size_t)rr * Hc + c4));
                __builtin_nontemporal_store(z,    (f32x4*)(tokp + (size_t)rr * Kc + c4));
            }
        }
        return;
    }

    // ---- GEMM path ----
    __shared__ unsigned short As[2][64 * PITCH];   // double-buffered A tile
    __shared__ float ssbuf[4][64];

    const int w    = tid >> 6;
    const int lane = tid & 63;
    const int l15  = lane & 15;
    const int quad = lane >> 4;

    f32x4 acc[4][8];                               // [ttile][ctile]
#pragma unroll
    for (int tt = 0; tt < 4; ++tt)
#pragma unroll
        for (int ct = 0; ct < 8; ++ct) acc[tt][ct] = (f32x4){0.f, 0.f, 0.f, 0.f};

    const float* xb = x + (size_t)b * (Sc * Dc);

    // Per-thread A staging coordinates (2 float4 chunks / thread / step)
    int a_r[2], a_c[2];  bool a_tv[2], a_lv[2];  const float* a_src[2];
#pragma unroll
    for (int it = 0; it < 2; ++it) {
        const int l = tid + it * 256;
        a_r[it] = l >> 3;                          // row in tile (0..63)
        a_c[it] = (l & 7) * 4;                     // k offset within 32-k tile
        const int t = t0 + a_r[it];
        a_tv[it] = (t < Tc);
        a_lv[it] = (t < ntok);                     // row fully valid iff t < ntok
        a_src[it] = xb + (size_t)t * (STRIDEc * Dc);  // token row = 512 contiguous floats
    }

    f32x4   ra[2];
    ushort8 rbA[8], rbB[8];

    // Per-lane B-fragment base: fragment (w,ct,l15,quad) is contiguous in Wt.
    const unsigned short* wfrag = Wt + ((w * 128 + l15) * 32 + quad * 8);

    // ---- prologue (step 0) ----
#pragma unroll
    for (int it = 0; it < 2; ++it) {
        ra[it] = (f32x4){0.f, 0.f, 0.f, 0.f};
        if (a_lv[it]) ra[it] = *(const f32x4*)(a_src[it] + a_c[it]);
    }
#pragma unroll
    for (int ct = 0; ct < 8; ++ct)
        rbA[ct] = *(const ushort8*)(wfrag + ct * 512);

    auto do_step = [&](const int step, ushort8 (&rbC)[8], ushort8 (&rbN)[8]) {
        const int p  = step & 1;
        const int k0 = step * 32;
        // commit staged A regs to LDS (+ tokens out; zeros for padding rows)
#pragma unroll
        for (int it = 0; it < 2; ++it) {
            const f32x4 v = ra[it];
            if (a_tv[it])
                __builtin_nontemporal_store(v,
                    (f32x4*)(tokb + (size_t)(t0 + a_r[it]) * Kc + k0 + a_c[it]));
            ushort4 h4;
            h4.x = f2bf(v[0]); h4.y = f2bf(v[1]); h4.z = f2bf(v[2]); h4.w = f2bf(v[3]);
            *(ushort4*)(&As[p][0] + a_r[it] * PITCH + a_c[it]) = h4;
        }
        __syncthreads();                            // As[p] ready; prior readers of As[p^1] retired
        // token fragments from LDS
        bf16x8 btok[4];
#pragma unroll
        for (int tt = 0; tt < 4; ++tt)
            btok[tt] = __builtin_bit_cast(bf16x8,
                *(const ushort8*)(&As[p][0] + (tt * 16 + l15) * PITCH + quad * 8));
        // prefetch next step (A from x, B fragments from Wt) under the MFMAs
        if (step < 15) {
            const int kn = k0 + 32;
#pragma unroll
            for (int it = 0; it < 2; ++it) {
                ra[it] = (f32x4){0.f, 0.f, 0.f, 0.f};
                if (a_lv[it]) ra[it] = *(const f32x4*)(a_src[it] + kn + a_c[it]);
            }
            const unsigned short* wn = wfrag + (size_t)(step + 1) * (Hc * 32);
#pragma unroll
            for (int ct = 0; ct < 8; ++ct)
                rbN[ct] = *(const ushort8*)(wn + ct * 512);
        }
        // MFMA (operand-swapped): aW straight from registers
#pragma unroll
        for (int ct = 0; ct < 8; ++ct) {
            const bf16x8 aW = __builtin_bit_cast(bf16x8, rbC[ct]);
#pragma unroll
            for (int tt = 0; tt < 4; ++tt)
                acc[tt][ct] = __builtin_amdgcn_mfma_f32_16x16x32_bf16(
                    aW, btok[tt], acc[tt][ct], 0, 0, 0);
        }
    };

#pragma unroll
    for (int sp = 0; sp < 8; ++sp) {               // 16 k-steps, rb parity-swapped
        do_step(2 * sp,     rbA, rbB);
        do_step(2 * sp + 1, rbB, rbA);
    }

    // ---- epilogue: bias, in-register row sums, RMS, scale, float4 stores ----
    float ss[4] = {0.f, 0.f, 0.f, 0.f};
#pragma unroll
    for (int ct = 0; ct < 8; ++ct) {
        const f32x4 b4 = *(const f32x4*)(bias + w * 128 + ct * 16 + quad * 4);
#pragma unroll
        for (int tt = 0; tt < 4; ++tt) {
            f32x4 h = acc[tt][ct] + b4;
            acc[tt][ct] = h;
            ss[tt] += h[0] * h[0] + h[1] * h[1] + h[2] * h[2] + h[3] * h[3];
        }
    }
#pragma unroll
    for (int tt = 0; tt < 4; ++tt) {
        float s = ss[tt];
        s += __shfl_xor(s, 16);
        s += __shfl_xor(s, 32);
        if (quad == 0) ssbuf[w][tt * 16 + l15] = s;
    }
    __syncthreads();
    float rstd[4];
#pragma unroll
    for (int tt = 0; tt < 4; ++tt) {
        const int r = tt * 16 + l15;
        const float tot = ssbuf[0][r] + ssbuf[1][r] + ssbuf[2][r] + ssbuf[3][r];
        rstd[tt] = rsqrtf(tot * (1.0f / (float)Hc) + EPSc);
    }
#pragma unroll
    for (int ct = 0; ct < 8; ++ct) {
        const f32x4 s4 = *(const f32x4*)(scale + w * 128 + ct * 16 + quad * 4);
#pragma unroll
        for (int tt = 0; tt < 4; ++tt) {
            const int t = t0 + tt * 16 + l15;
            if (t < Tc) {
                f32x4 o = acc[tt][ct] * rstd[tt] * s4;
                __builtin_nontemporal_store(o,
                    (f32x4*)(hidden + ((size_t)b * Tc + t) * Hc
                             + w * 128 + ct * 16 + quad * 4));
            }
        }
    }
}

extern "C" void kernel_launch(void* const* d_in, const int* in_sizes, int n_in,
                              void* d_out, int out_size, void* d_ws, size_t ws_size,
                              hipStream_t stream) {
    const float* x       = (const float*)d_in[0];
    const int*   lengths = (const int*)d_in[1];
    const float* W       = (const float*)d_in[2];
    const float* bias    = (const float*)d_in[3];
    const float* scale   = (const float*)d_in[4];

    const size_t BTH = (size_t)Bc * Tc * Hc;   // 16,760,832
    float* out    = (float*)d_out;
    float* hidden = out;                        // output 0
    float* tl     = out + BTH;                  // output 1 (32 floats)
    float* tokens = out + BTH + Bc;             // output 2

    unsigned short* Wt = (unsigned short*)d_ws; // 512x512 bf16 = 512 KB, k-slice-packed

    {   // W -> Wt (transpose + bf16 + slice-pack) and token_lengths
        dim3 grid(Hc / 32, Hc / 32);            // (16,16)
        prep_kernel<<<grid, 256, 0, stream>>>(W, lengths, Wt, tl);
    }
    {   // fused tokens + GEMM + RMSNorm (fast path for all-padding blocks)
        dim3 grid(16, Bc);                      // 16 m-blocks x 32 batches
        fused_kernel<<<grid, 256, 0, stream>>>(x, lengths, Wt, bias, scale,
                                               hidden, tokens);
    }
}